// Round 10
// baseline (262.338 us; speedup 1.0000x reference)
//
#include <hip/hip_runtime.h>
#include <cmath>

// PSNR + 3D-SSIM, pred/gt (N=4, C=16->D, H=512, W=512) f32.
// R18 = R16/R17 base (dot2 H/W blurs, XCD swizzle, 154-159us) with the LDS
// pipe (measured binding resource: ~13.3 b128/px-slice ~= 65us + 33us
// conflicts) and VALU cut together:
//  1) W-blur: 2 adjacent px per thread (both need the SAME 6 col-pair
//     words; even px uses ge, odd go). 128 threads (waves 2-3) x 6 reads
//     -> W LDS ops halve. H stays on waves 0-1; waves 0-1 overlap
//     stage(d+1) with W(d) (disjoint LDS buffers, B1 fences H).
//  2) D-blur -> R12's verified MFMA epilogue (Ostack[ch][px][d16] f16 with
//     Q^(2*(px>>6&1)) quad swizzle + WL A-fragment D-GEMM): removes 32
//     pk_fma/px/slice AND the 64-reg accumulator file. Only the epilogue
//     uses MFMA -- the slice loop keeps the dense VALU/LDS body, so R12's
//     starvation mode doesn't apply.
// Everything else (stage, H, barriers, prefetch, swizzle, PSNR) verbatim.

#define NB 4
#define DD 16
#define HH 512
#define WW 512
#define SLICE (HH * WW)
#define VOL (DD * SLICE)
#define C1F 0.0001f
#define C2F 0.0009f

#define TH 16
#define TW 16
#define SCOLS 26            // staged cols (TW+10)
#define NRP 13              // staged row-pairs ((TH+10)/2)
#define PW 14               // uint4 words per col-parity plane (13 + pad)
#define PLSTR 28            // row-pair stride (2 planes)
#define SDW (NRP * PLSTR)   // 364 uint4 = 5824 B
#define TMW (TH * PW)       // 224 uint4 = 3584 B
#define NTHR 256
#define SIT (NRP * SCOLS)   // 338 stage items per slice
#define XTRA (SIT - NTHR)   // 82
#define HITEMS 104          // 8 out-row-pairs x 13 col-pairs

typedef _Float16 h2v __attribute__((ext_vector_type(2)));
typedef _Float16 h8 __attribute__((ext_vector_type(8)));
typedef float f4 __attribute__((ext_vector_type(4)));

struct KArg {
  unsigned ge[6], go[6];   // f16x2 tap-pair coeffs, even/odd phase (renorm'd)
  unsigned wlf[256];       // 64 lanes x uint4: WL A-frag A[m=lo][k=8hi+i]
};

__device__ inline float dot2h(unsigned a, unsigned b, float c) {
#if __has_builtin(__builtin_amdgcn_fdot2)
  return __builtin_amdgcn_fdot2(__builtin_bit_cast(h2v, a),
                                __builtin_bit_cast(h2v, b), c, false);
#else
  h2v av = __builtin_bit_cast(h2v, a), bv = __builtin_bit_cast(h2v, b);
  return fmaf((float)av.y, (float)bv.y, fmaf((float)av.x, (float)bv.x, c));
#endif
}
__device__ inline f4 mfma16(uint4 a, uint4 b, f4 c) {
  return __builtin_amdgcn_mfma_f32_16x16x32_f16(
      __builtin_bit_cast(h8, a), __builtin_bit_cast(h8, b), c, 0, 0, 0);
}
__device__ inline unsigned pkh(float a, float b) {
  return __builtin_bit_cast(unsigned, __builtin_amdgcn_cvt_pkrtz(a, b));
}
__device__ inline int iclamp(int v, int lo, int hi) {
  return v < lo ? lo : (v > hi ? hi : v);
}

__device__ inline float block_sum256(float v) {
#pragma unroll
  for (int o = 32; o > 0; o >>= 1) v += __shfl_down(v, o, 64);
  __shared__ float r[4];
  if ((threadIdx.x & 63) == 0) r[threadIdx.x >> 6] = v;
  __syncthreads();
  float out = 0.f;
  if (threadIdx.x == 0) {
#pragma unroll
    for (int i = 0; i < 4; ++i) out += r[i];
  }
  __syncthreads();
  return out;
}

__global__ void zero_acc_k(float* acc) {
  if (threadIdx.x < 8) acc[threadIdx.x] = 0.f;
}

__global__ __launch_bounds__(NTHR, 3) void fused_k(
    const float* __restrict__ pred, const float* __restrict__ gt,
    float* __restrict__ acc, KArg ka) {
  __shared__ uint4 sd[SDW];               // staged slice        5.8 KB
  __shared__ uint4 tmp[TMW];              // H-blurred           3.6 KB
  __shared__ _Float16 ost[4 * 256 * 16];  // Ostack              32 KB
  __shared__ uint4 zzq;                   // zeros for K-pad reads

  // XCD-aware bijective swizzle (kept from R16: FETCH 257->78 MB)
  int b0 = blockIdx.x;
  int b = (b0 & 7) * ((NB * 1024) >> 3) + (b0 >> 3);
  int tile = b & 1023;               // 32 h-tiles x 32 w-tiles
  int n = b >> 10;
  int th0 = (tile >> 5) * TH;
  int tw0 = (tile & 31) * TW;
  int t = threadIdx.x;
  int lane = t & 63, wv = t >> 6;
  int lo = lane & 15, hi = lane >> 4;

  if (t == 0) zzq = make_uint4(0, 0, 0, 0);

  // ---- stage metadata, slot 0 (item t, always < 338)
  int rp0 = t / SCOLS, x0 = t - rp0 * SCOLS;
  int gx0 = iclamp(tw0 + x0 - 5, 0, WW - 1);
  int go0a = iclamp(th0 + 2 * rp0 - 5, 0, HH - 1) * WW + gx0;
  int go0b = iclamp(th0 + 2 * rp0 - 4, 0, HH - 1) * WW + gx0;
  int w0i = (2 * rp0 + (x0 & 1)) * PW + (x0 >> 1);
  bool ox0 = (x0 >= 5) && (x0 < 5 + TW);
  float o0a = (ox0 && rp0 >= 3 && rp0 <= 10) ? 1.f : 0.f;
  float o0b = (ox0 && rp0 >= 2 && rp0 <= 9) ? 1.f : 0.f;
  // slot 1 (items 256..337 -> threads 174..255)
  int i1 = t + XTRA;
  bool has2 = (i1 >= NTHR);
  int rp1 = i1 / SCOLS, x1 = i1 - rp1 * SCOLS;
  int gx1 = iclamp(tw0 + x1 - 5, 0, WW - 1);
  int go1a = iclamp(th0 + 2 * rp1 - 5, 0, HH - 1) * WW + gx1;
  int go1b = iclamp(th0 + 2 * rp1 - 4, 0, HH - 1) * WW + gx1;
  int w1i = (2 * rp1 + (x1 & 1)) * PW + (x1 >> 1);
  bool ox1 = (x1 >= 5) && (x1 < 5 + TW);
  float o1a = (ox1 && rp1 >= 3 && rp1 <= 10) ? 1.f : 0.f;
  float o1b = (ox1 && rp1 >= 2 && rp1 <= 9) ? 1.f : 0.f;

  // ---- H metadata (waves 0-1): item = (row-pair hm, col-pair hcp)
  bool hasH = (t < HITEMS);
  int hm = t & 7, hcp = t >> 3;
  int hrd = hm * PLSTR + hcp;
  int hwr = (2 * hm) * PW + hcp;

  // ---- W metadata (waves 2-3): thread owns px pair (wy, 2wxh / 2wxh+1)
  bool hasW = (t >= 128);
  int u = (t - 128) & 127;
  int wy = u >> 3, wxh = u & 7;
  int wrd = wy * PW + wxh;                 // window col-pairs wxh..wxh+5
  int px0 = wy * 16 + 2 * wxh;
  int qx = 2 * ((wy >> 2) & 1);            // = 2*((px0>>6)&1)
  int owb0 = px0 * 4;                      // u64 units, ch0 base

  const float* pb = pred + (size_t)n * VOL;
  const float* qb = gt + (size_t)n * VOL;

  // prefetch slice 0
  float p0a = pb[go0a], p0b = pb[go0b], q0a = qb[go0a], q0b = qb[go0b];
  float p1a = 0.f, p1b = 0.f, q1a = 0.f, q1b = 0.f;
  if (has2) { p1a = pb[go1a]; p1b = pb[go1b]; q1a = qb[go1a]; q1b = qb[go1b]; }

  float psnr = 0.f;
  // pack state (only live on waves 2-3): even-slice saves + d-pair packs
  float se0 = 0, se1 = 0, se2 = 0, se3 = 0, so0 = 0, so1 = 0, so2 = 0, so3 = 0;
  unsigned pAe0 = 0, pAe1 = 0, pAe2 = 0, pAe3 = 0;
  unsigned pAo0 = 0, pAo1 = 0, pAo2 = 0, pAo3 = 0;

  __syncthreads();   // zzq visible

#pragma unroll 1
  for (int d = 0; d < DD; ++d) {
    // ---- stage slice d (all threads)
    {
      float SA = p0a + q0a, DA = p0a - q0a;
      float SB = p0b + q0b, DB = p0b - q0b;
      float dA = DA * DA, dB = DB * DB;
      psnr = fmaf(o0a, dA, psnr);
      psnr = fmaf(o0b, dB, psnr);
      sd[w0i] = make_uint4(pkh(SA, SB), pkh(DA, DB),
                           pkh(SA * SA, SB * SB), pkh(dA, dB));
    }
    if (has2) {
      float SA = p1a + q1a, DA = p1a - q1a;
      float SB = p1b + q1b, DB = p1b - q1b;
      float dA = DA * DA, dB = DB * DB;
      psnr = fmaf(o1a, dA, psnr);
      psnr = fmaf(o1b, dB, psnr);
      sd[w1i] = make_uint4(pkh(SA, SB), pkh(DA, DB),
                           pkh(SA * SA, SB * SB), pkh(dA, dB));
    }
    __syncthreads();   // B1: sd ready; fences tmp vs prev W reads

    // prefetch slice d+1
    if (d < DD - 1) {
      const float* P = pb + (size_t)(d + 1) * SLICE;
      const float* Q = qb + (size_t)(d + 1) * SLICE;
      p0a = P[go0a]; p0b = P[go0b]; q0a = Q[go0a]; q0b = Q[go0b];
      if (has2) { p1a = P[go1a]; p1b = P[go1b]; q1a = Q[go1a]; q1b = Q[go1b]; }
    }

    // ---- H-blur (waves 0-1): 12 b128 reads -> 2 b128 writes
    if (hasH) {
      float e0[4] = {0, 0, 0, 0}, e1[4] = {0, 0, 0, 0};
      float r0[4] = {0, 0, 0, 0}, r1[4] = {0, 0, 0, 0};
#pragma unroll
      for (int J = 0; J < 6; ++J) {
        uint4 ve = sd[hrd + J * PLSTR];
        uint4 vo = sd[hrd + J * PLSTR + PW];
        unsigned cge = ka.ge[J], cgo = ka.go[J];
        e0[0] = dot2h(cge, ve.x, e0[0]); e0[1] = dot2h(cge, ve.y, e0[1]);
        e0[2] = dot2h(cge, ve.z, e0[2]); e0[3] = dot2h(cge, ve.w, e0[3]);
        r0[0] = dot2h(cgo, ve.x, r0[0]); r0[1] = dot2h(cgo, ve.y, r0[1]);
        r0[2] = dot2h(cgo, ve.z, r0[2]); r0[3] = dot2h(cgo, ve.w, r0[3]);
        e1[0] = dot2h(cge, vo.x, e1[0]); e1[1] = dot2h(cge, vo.y, e1[1]);
        e1[2] = dot2h(cge, vo.z, e1[2]); e1[3] = dot2h(cge, vo.w, e1[3]);
        r1[0] = dot2h(cgo, vo.x, r1[0]); r1[1] = dot2h(cgo, vo.y, r1[1]);
        r1[2] = dot2h(cgo, vo.z, r1[2]); r1[3] = dot2h(cgo, vo.w, r1[3]);
      }
      tmp[hwr] = make_uint4(pkh(e0[0], e1[0]), pkh(e0[1], e1[1]),
                            pkh(e0[2], e1[2]), pkh(e0[3], e1[3]));
      tmp[hwr + PW] = make_uint4(pkh(r0[0], r1[0]), pkh(r0[1], r1[1]),
                                 pkh(r0[2], r1[2]), pkh(r0[3], r1[3]));
    }
    __syncthreads();   // B2: tmp ready; separates sd reads from next stage

    // ---- W-blur (waves 2-3): 2 px from the SAME 6 words; pack into ost
    if (hasW) {
      float e0 = 0, e1 = 0, e2 = 0, e3 = 0;   // even px (uses ge)
      float o0 = 0, o1 = 0, o2 = 0, o3 = 0;   // odd px (uses go)
#pragma unroll
      for (int J = 0; J < 6; ++J) {
        uint4 v = tmp[wrd + J];
        unsigned cE = ka.ge[J], cO = ka.go[J];
        e0 = dot2h(cE, v.x, e0); e1 = dot2h(cE, v.y, e1);
        e2 = dot2h(cE, v.z, e2); e3 = dot2h(cE, v.w, e3);
        o0 = dot2h(cO, v.x, o0); o1 = dot2h(cO, v.y, o1);
        o2 = dot2h(cO, v.z, o2); o3 = dot2h(cO, v.w, o3);
      }
      if ((d & 1) == 0) {
        se0 = e0; se1 = e1; se2 = e2; se3 = e3;
        so0 = o0; so1 = o1; so2 = o2; so3 = o3;
      } else if ((d & 2) == 0) {
        pAe0 = pkh(se0, e0); pAe1 = pkh(se1, e1);
        pAe2 = pkh(se2, e2); pAe3 = pkh(se3, e3);
        pAo0 = pkh(so0, o0); pAo1 = pkh(so1, o1);
        pAo2 = pkh(so2, o2); pAo3 = pkh(so3, o3);
      } else {
        int Qp = (d >> 2) ^ qx;
        uint2* op = (uint2*)ost;
        op[owb0 + Qp]        = make_uint2(pAe0, pkh(se0, e0));
        op[owb0 + 1024 + Qp] = make_uint2(pAe1, pkh(se1, e1));
        op[owb0 + 2048 + Qp] = make_uint2(pAe2, pkh(se2, e2));
        op[owb0 + 3072 + Qp] = make_uint2(pAe3, pkh(se3, e3));
        op[owb0 + 4 + Qp]        = make_uint2(pAo0, pkh(so0, o0));
        op[owb0 + 4 + 1024 + Qp] = make_uint2(pAo1, pkh(so1, o1));
        op[owb0 + 4 + 2048 + Qp] = make_uint2(pAo2, pkh(so2, o2));
        op[owb0 + 4 + 3072 + Qp] = make_uint2(pAo3, pkh(so3, o3));
      }
    }
  }
  __syncthreads();   // Ostack complete (cross-wave)

  // ---- epilogue: D-GEMM (A = WL fragment) + SSIM (verbatim R12/R13)
  uint4 wlf = ((const uint4*)ka.wlf)[lane];
  const uint4* oq = (const uint4*)ost;
  f4 z4 = {0.f, 0.f, 0.f, 0.f};
  int bnt = wv & 1;
  int blk = (hi < 2) ? (hi ^ bnt) : 0;
  bool real = (hi < 2);
  float ssum = 0.f;
#pragma unroll
  for (int q = 0; q < 4; ++q) {
    int nt = 4 * wv + q;
    int bidx = (16 * nt + lo) * 2 + blk;
    const uint4* bp0 = real ? &oq[bidx] : &zzq;
    const uint4* bp1 = real ? &oq[512 + bidx] : &zzq;
    const uint4* bp2 = real ? &oq[1024 + bidx] : &zzq;
    const uint4* bp3 = real ? &oq[1536 + bidx] : &zzq;
    f4 cS = mfma16(wlf, *bp0, z4);
    f4 cD = mfma16(wlf, *bp1, z4);
    f4 cS2 = mfma16(wlf, *bp2, z4);
    f4 cD2 = mfma16(wlf, *bp3, z4);
#pragma unroll
    for (int r = 0; r < 4; ++r) {
      float Sb = cS[r], Db = cD[r], B1 = cS2[r], B2 = cD2[r];
      float SS = Sb * Sb, DDm = Db * Db;
      float m12_2 = (SS - DDm) * 0.5f;
      float msq = (SS + DDm) * 0.5f;
      float Epq = (B1 - B2) * 0.25f;
      float Esum = (B1 + B2) * 0.5f;
      float sig12_2 = 2.f * Epq - m12_2;
      float svar = Esum - msq;
      float num = (m12_2 + C1F) * (sig12_2 + C2F);
      float den = (msq + C1F) * (svar + C2F);
      ssum += num / den;
    }
  }
  float bs = block_sum256(ssum);
  if (t == 0) atomicAdd(&acc[4 + n], bs);
  float bp = block_sum256(psnr);
  if (t == 0) atomicAdd(&acc[n], bp);
}

__global__ void final_k(const float* __restrict__ acc, float* __restrict__ out) {
  if (threadIdx.x == 0 && blockIdx.x == 0) {
    double psnr = 0.0, ssim = 0.0;
    for (int n = 0; n < NB; ++n) {
      double mse = (double)acc[n] / (double)VOL;
      psnr += 10.0 * log10(1.0 / mse);
      ssim += (double)acc[4 + n] / (double)VOL;
    }
    out[0] = (float)psnr;
    out[1] = (float)ssim;
    out[2] = (float)NB;
  }
}

// host f32 -> f16 (round-to-nearest-even)
static unsigned short f2h(float f) {
  union { float f; unsigned u; } v; v.f = f;
  unsigned u = v.u;
  unsigned s = (u >> 16) & 0x8000u;
  int e = (int)((u >> 23) & 0xff) - 127 + 15;
  unsigned m = u & 0x7fffffu;
  if (e <= 0) return (unsigned short)s;
  if (e >= 31) return (unsigned short)(s | 0x7c00u);
  unsigned h = ((unsigned)e << 10) | (m >> 13);
  unsigned rem = m & 0x1fffu;
  if (rem > 0x1000u || (rem == 0x1000u && (h & 1u))) h++;
  return (unsigned short)(s | h);
}
// host f16 -> f32 (normals + zero)
static float h2f(unsigned short h) {
  unsigned se = (h >> 10) & 0x1f, m = h & 0x3ffu, s = ((unsigned)h & 0x8000u) << 16;
  union { unsigned u; float f; } v;
  if (se == 0) { v.u = s; return v.f; }
  v.u = s | ((se - 15 + 127) << 23) | (m << 13);
  return v.f;
}

extern "C" void kernel_launch(void* const* d_in, const int* in_sizes, int n_in,
                              void* d_out, int out_size, void* d_ws, size_t ws_size,
                              hipStream_t stream) {
  const float* pred = (const float*)d_in[0];
  const float* gt = (const float*)d_in[1];
  float* acc = (float*)d_ws;    // 8 floats

  double tt[11], s = 0.0;
  for (int i = 0; i < 11; ++i) {
    double x = i - 5;
    tt[i] = exp(-(x * x) / 4.5);
    s += tt[i];
  }
  float g[11];
  for (int i = 0; i < 11; ++i) g[i] = (float)(tt[i] / s);

  // f16 taps renormalized so the f16 values sum exactly to 1
  unsigned short hg[11];
  for (int i = 0; i < 11; ++i) hg[i] = f2h(g[i]);
  for (int pass = 0; pass < 3; ++pass) {
    double sum = 0.0;
    for (int i = 0; i < 11; ++i) sum += (double)h2f(hg[i]);
    hg[5] = f2h((float)((double)h2f(hg[5]) + (1.0 - sum)));
  }

  KArg ka;
  // even phase: (g0,g1)(g2,g3)(g4,g5)(g6,g7)(g8,g9)(g10,0)
  for (int j = 0; j < 5; ++j)
    ka.ge[j] = (unsigned)hg[2 * j] | ((unsigned)hg[2 * j + 1] << 16);
  ka.ge[5] = (unsigned)hg[10];
  // odd phase: (0,g0)(g1,g2)(g3,g4)(g5,g6)(g7,g8)(g9,g10)
  ka.go[0] = ((unsigned)hg[0]) << 16;
  for (int j = 1; j < 6; ++j)
    ka.go[j] = (unsigned)hg[2 * j - 1] | ((unsigned)hg[2 * j] << 16);

  // clamp-folded D-blur weights wl[d][o]; f16 per-dout renorm
  float wl[DD][DD];
  for (int o = 0; o < DD; ++o)
    for (int d = 0; d < DD; ++d) {
      float w = 0.f;
      for (int k = 0; k < 11; ++k) {
        int j = o + k - 5;
        j = j < 0 ? 0 : (j > 15 ? 15 : j);
        if (j == d) w += g[k];
      }
      wl[d][o] = w;
    }
  unsigned short wlh[DD][DD];   // wlh[o][d]
  for (int o = 0; o < DD; ++o) {
    int dmx = 0;
    for (int d = 0; d < DD; ++d) {
      wlh[o][d] = f2h(wl[d][o]);
      if (wl[d][o] > wl[dmx][o]) dmx = d;
    }
    for (int pass = 0; pass < 3; ++pass) {
      double sum = 0.0;
      for (int d = 0; d < DD; ++d) sum += (double)h2f(wlh[o][d]);
      wlh[o][dmx] = f2h((float)((double)h2f(wlh[o][dmx]) + (1.0 - sum)));
    }
  }
  // WL A-fragment: A[m=lo][k=8hi+i], zero for hi>=2 (K pad)
  for (int l = 0; l < 64; ++l) {
    int lo = l & 15, hi = l >> 4;
    unsigned short v[8];
    for (int i = 0; i < 8; ++i)
      v[i] = (hi < 2) ? wlh[lo][8 * hi + i] : 0;
    for (int k = 0; k < 4; ++k)
      ka.wlf[l * 4 + k] = (unsigned)v[2 * k] | ((unsigned)v[2 * k + 1] << 16);
  }

  zero_acc_k<<<1, 64, 0, stream>>>(acc);
  fused_k<<<NB * 1024, NTHR, 0, stream>>>(pred, gt, acc, ka);
  final_k<<<1, 1, 0, stream>>>(acc, (float*)d_out);
}

// Round 11
// 253.483 us; speedup vs baseline: 1.0349x; 1.0349x over previous
//
#include <hip/hip_runtime.h>
#include <cmath>

// PSNR + 3D-SSIM, pred/gt (N=4, C=16->D, H=512, W=512) f32.
// R19 = R16 byte-for-byte (best fused: 154.5us; dot2 H/W blurs, XCD
// swizzle, W reads as 2-lane broadcast pairs) + exactly ONE verified-good
// piece from R17: packed-f32 D-accumulate (f32x2 accumulators +
// v_pk_fma_f32, 64 fma/slice -> 32 pk_fma/slice, ~-17% hot-loop VALU).
// R17's W remap (its other piece) is NOT taken: it raised W-read bank
// conflicts from 4-way to 8-way (+6M conflict-cycles, fused +4.5us).
// R18's role-split/ost scheme raised conflicts to 30M -- abandoned.

#define NB 4
#define DD 16
#define HH 512
#define WW 512
#define SLICE (HH * WW)
#define VOL (DD * SLICE)
#define C1F 0.0001f
#define C2F 0.0009f

#define TH 16
#define TW 16
#define SCOLS 26            // staged cols (TW+10)
#define NRP 13              // staged row-pairs ((TH+10)/2)
#define PW 14               // uint4 words per col-parity plane (13 + pad)
#define PLSTR 28            // row-pair stride (2 planes)
#define SDW (NRP * PLSTR)   // 364 uint4 = 5824 B
#define TMW (TH * PW)       // 224 uint4 = 3584 B
#define NTHR 256
#define SIT (NRP * SCOLS)   // 338 stage items per slice
#define XTRA (SIT - NTHR)   // 82
#define HITEMS 104          // 8 out-row-pairs x 13 col-pairs

typedef _Float16 h2v __attribute__((ext_vector_type(2)));
typedef float f32x2 __attribute__((ext_vector_type(2)));

struct KArg {
  unsigned ge[6], go[6];   // f16x2 tap-pair coeffs, even/odd phase (renorm'd)
  float wlT[DD * DD];      // wlT[d*16+dout] = clamp-folded D weight (f32)
};

__device__ inline float dot2h(unsigned a, unsigned b, float c) {
#if __has_builtin(__builtin_amdgcn_fdot2)
  return __builtin_amdgcn_fdot2(__builtin_bit_cast(h2v, a),
                                __builtin_bit_cast(h2v, b), c, false);
#else
  h2v av = __builtin_bit_cast(h2v, a), bv = __builtin_bit_cast(h2v, b);
  return fmaf((float)av.y, (float)bv.y, fmaf((float)av.x, (float)bv.x, c));
#endif
}
__device__ inline unsigned pkh(float a, float b) {
  return __builtin_bit_cast(unsigned, __builtin_amdgcn_cvt_pkrtz(a, b));
}
__device__ inline int iclamp(int v, int lo, int hi) {
  return v < lo ? lo : (v > hi ? hi : v);
}

__device__ inline float block_sum256(float v) {
#pragma unroll
  for (int o = 32; o > 0; o >>= 1) v += __shfl_down(v, o, 64);
  __shared__ float r[4];
  if ((threadIdx.x & 63) == 0) r[threadIdx.x >> 6] = v;
  __syncthreads();
  float out = 0.f;
  if (threadIdx.x == 0) {
#pragma unroll
    for (int i = 0; i < 4; ++i) out += r[i];
  }
  __syncthreads();
  return out;
}

__global__ void zero_acc_k(float* acc) {
  if (threadIdx.x < 8) acc[threadIdx.x] = 0.f;
}

__global__ __launch_bounds__(NTHR, 3) void fused_k(
    const float* __restrict__ pred, const float* __restrict__ gt,
    float* __restrict__ acc, KArg ka) {
  __shared__ uint4 sd[SDW];    // single-buffered staged slice
  __shared__ uint4 tmp[TMW];   // H-blurred

  // XCD-aware bijective swizzle (kept from R16: FETCH 257->78 MB)
  int b0 = blockIdx.x;
  int b = (b0 & 7) * ((NB * 1024) >> 3) + (b0 >> 3);
  int tile = b & 1023;               // 32 h-tiles x 32 w-tiles
  int n = b >> 10;
  int th0 = (tile >> 5) * TH;
  int tw0 = (tile & 31) * TW;
  int t = threadIdx.x;

  // ---- stage metadata, slot 0 (item t, always < 338)
  int rp0 = t / SCOLS, x0 = t - rp0 * SCOLS;
  int gx0 = iclamp(tw0 + x0 - 5, 0, WW - 1);
  int go0a = iclamp(th0 + 2 * rp0 - 5, 0, HH - 1) * WW + gx0;
  int go0b = iclamp(th0 + 2 * rp0 - 4, 0, HH - 1) * WW + gx0;
  int w0i = (2 * rp0 + (x0 & 1)) * PW + (x0 >> 1);
  bool ox0 = (x0 >= 5) && (x0 < 5 + TW);
  float o0a = (ox0 && rp0 >= 3 && rp0 <= 10) ? 1.f : 0.f;  // row 2rp-5 owned
  float o0b = (ox0 && rp0 >= 2 && rp0 <= 9) ? 1.f : 0.f;   // row 2rp-4 owned
  // slot 1 (items 256..337 -> threads 174..255)
  int i1 = t + XTRA;
  bool has2 = (i1 >= NTHR);
  int rp1 = i1 / SCOLS, x1 = i1 - rp1 * SCOLS;
  int gx1 = iclamp(tw0 + x1 - 5, 0, WW - 1);
  int go1a = iclamp(th0 + 2 * rp1 - 5, 0, HH - 1) * WW + gx1;
  int go1b = iclamp(th0 + 2 * rp1 - 4, 0, HH - 1) * WW + gx1;
  int w1i = (2 * rp1 + (x1 & 1)) * PW + (x1 >> 1);
  bool ox1 = (x1 >= 5) && (x1 < 5 + TW);
  float o1a = (ox1 && rp1 >= 3 && rp1 <= 10) ? 1.f : 0.f;
  float o1b = (ox1 && rp1 >= 2 && rp1 <= 9) ? 1.f : 0.f;

  // ---- H metadata: item = (out-row-pair hm, col-pair hcp), m-minor
  bool hasH = (t < HITEMS);
  int hm = t & 7, hcp = t >> 3;
  int hrd = hm * PLSTR + hcp;        // plane0 read base (tap J adds J*PLSTR)
  int hwr = (2 * hm) * PW + hcp;     // row 2m write (+PW for row 2m+1)

  // ---- W metadata: thread owns px (t>>4, t&15) -- R16 mapping (broadcast
  // pairs on tmp reads: 4 distinct addrs/bank-group, ~free)
  int wx = t & 15;
  int wrd = (t >> 4) * PW + (wx >> 1);
  unsigned cw[6];
#pragma unroll
  for (int J = 0; J < 6; ++J) cw[J] = (wx & 1) ? ka.go[J] : ka.ge[J];

  const float* pb = pred + (size_t)n * VOL;
  const float* qb = gt + (size_t)n * VOL;

  // prefetch slice 0
  float p0a = pb[go0a], p0b = pb[go0b], q0a = qb[go0a], q0b = qb[go0b];
  float p1a = 0.f, p1b = 0.f, q1a = 0.f, q1b = 0.f;
  if (has2) { p1a = pb[go1a]; p1b = pb[go1b]; q1a = qb[go1a]; q1b = qb[go1b]; }

  float psnr = 0.f;
  f32x2 A01[DD], A23[DD];            // {a0,a1} and {a2,a3} channel pairs
#pragma unroll
  for (int j = 0; j < DD; ++j) {
    A01[j] = (f32x2){0.f, 0.f};
    A23[j] = (f32x2){0.f, 0.f};
  }

#pragma unroll 1
  for (int d = 0; d < DD; ++d) {
    // ---- stage slice d (f16 row-pair packed, AoS uint4)
    {
      float SA = p0a + q0a, DA = p0a - q0a;
      float SB = p0b + q0b, DB = p0b - q0b;
      float dA = DA * DA, dB = DB * DB;
      psnr = fmaf(o0a, dA, psnr);
      psnr = fmaf(o0b, dB, psnr);
      sd[w0i] = make_uint4(pkh(SA, SB), pkh(DA, DB),
                           pkh(SA * SA, SB * SB), pkh(dA, dB));
    }
    if (has2) {
      float SA = p1a + q1a, DA = p1a - q1a;
      float SB = p1b + q1b, DB = p1b - q1b;
      float dA = DA * DA, dB = DB * DB;
      psnr = fmaf(o1a, dA, psnr);
      psnr = fmaf(o1b, dB, psnr);
      sd[w1i] = make_uint4(pkh(SA, SB), pkh(DA, DB),
                           pkh(SA * SA, SB * SB), pkh(dA, dB));
    }
    __syncthreads();   // B1: sd ready; also fences tmp vs prev iter's W reads

    // prefetch slice d+1 (hides under H+W; consumed next iter after B2+W)
    if (d < DD - 1) {
      const float* P = pb + (size_t)(d + 1) * SLICE;
      const float* Q = qb + (size_t)(d + 1) * SLICE;
      p0a = P[go0a]; p0b = P[go0b]; q0a = Q[go0a]; q0b = Q[go0b];
      if (has2) { p1a = P[go1a]; p1b = P[go1b]; q1a = Q[go1a]; q1b = Q[go1b]; }
    }

    // ---- H-blur (vertical), fused row parities: 12 b128 reads -> 2 writes
    if (hasH) {
      float e0[4] = {0, 0, 0, 0}, e1[4] = {0, 0, 0, 0};   // row 2m, col 2cp / 2cp+1
      float r0[4] = {0, 0, 0, 0}, r1[4] = {0, 0, 0, 0};   // row 2m+1
#pragma unroll
      for (int J = 0; J < 6; ++J) {
        uint4 ve = sd[hrd + J * PLSTR];        // col 2cp,  row-pair m+J
        uint4 vo = sd[hrd + J * PLSTR + PW];   // col 2cp+1
        unsigned cge = ka.ge[J], cgo = ka.go[J];
        e0[0] = dot2h(cge, ve.x, e0[0]); e0[1] = dot2h(cge, ve.y, e0[1]);
        e0[2] = dot2h(cge, ve.z, e0[2]); e0[3] = dot2h(cge, ve.w, e0[3]);
        r0[0] = dot2h(cgo, ve.x, r0[0]); r0[1] = dot2h(cgo, ve.y, r0[1]);
        r0[2] = dot2h(cgo, ve.z, r0[2]); r0[3] = dot2h(cgo, ve.w, r0[3]);
        e1[0] = dot2h(cge, vo.x, e1[0]); e1[1] = dot2h(cge, vo.y, e1[1]);
        e1[2] = dot2h(cge, vo.z, e1[2]); e1[3] = dot2h(cge, vo.w, e1[3]);
        r1[0] = dot2h(cgo, vo.x, r1[0]); r1[1] = dot2h(cgo, vo.y, r1[1]);
        r1[2] = dot2h(cgo, vo.z, r1[2]); r1[3] = dot2h(cgo, vo.w, r1[3]);
      }
      tmp[hwr] = make_uint4(pkh(e0[0], e1[0]), pkh(e0[1], e1[1]),
                            pkh(e0[2], e1[2]), pkh(e0[3], e1[3]));
      tmp[hwr + PW] = make_uint4(pkh(r0[0], r1[0]), pkh(r0[1], r1[1]),
                                 pkh(r0[2], r1[2]), pkh(r0[3], r1[3]));
    }
    __syncthreads();   // B2: tmp ready; also separates H's sd reads from the
                       // NEXT iteration's stage writes (single buffer safe)

    // ---- W-blur at owned px: 6 b128 reads (2-way broadcast), 24 dot2
    float w0 = 0.f, w1 = 0.f, w2 = 0.f, w3 = 0.f;
#pragma unroll
    for (int J = 0; J < 6; ++J) {
      uint4 v = tmp[wrd + J];
      w0 = dot2h(cw[J], v.x, w0); w1 = dot2h(cw[J], v.y, w1);
      w2 = dot2h(cw[J], v.z, w2); w3 = dot2h(cw[J], v.w, w3);
    }
    // ---- D-accumulate: packed f32 (v_pk_fma_f32), weights SGPR-uniform
    const float* wl = ka.wlT + d * DD;
    f32x2 W01 = {w0, w1}, W23 = {w2, w3};
#pragma unroll
    for (int o = 0; o < DD; ++o) {
      float w = wl[o];
      f32x2 ws = {w, w};
      A01[o] = __builtin_elementwise_fma(ws, W01, A01[o]);
      A23[o] = __builtin_elementwise_fma(ws, W23, A23[o]);
    }
  }

  // ---- SSIM over the 16 douts of this px
  float ssum = 0.f;
#pragma unroll
  for (int j = 0; j < DD; ++j) {
    float Sb = A01[j].x, Db = A01[j].y, B1 = A23[j].x, B2 = A23[j].y;
    float SS = Sb * Sb, DDm = Db * Db;
    float m12_2 = (SS - DDm) * 0.5f;     // 2*mu1*mu2
    float msq   = (SS + DDm) * 0.5f;     // mu1^2 + mu2^2
    float Epq   = (B1 - B2) * 0.25f;     // E[pq]
    float Esum  = (B1 + B2) * 0.5f;      // E[p^2+q^2]
    float sig12_2 = 2.f * Epq - m12_2;   // 2*sigma12
    float svar    = Esum - msq;          // sigma1^2 + sigma2^2
    float num = (m12_2 + C1F) * (sig12_2 + C2F);
    float den = (msq + C1F) * (svar + C2F);
    ssum += num / den;
  }
  float bs = block_sum256(ssum);
  if (t == 0) atomicAdd(&acc[4 + n], bs);
  float bp = block_sum256(psnr);
  if (t == 0) atomicAdd(&acc[n], bp);
}

__global__ void final_k(const float* __restrict__ acc, float* __restrict__ out) {
  if (threadIdx.x == 0 && blockIdx.x == 0) {
    double psnr = 0.0, ssim = 0.0;
    for (int n = 0; n < NB; ++n) {
      double mse = (double)acc[n] / (double)VOL;
      psnr += 10.0 * log10(1.0 / mse);
      ssim += (double)acc[4 + n] / (double)VOL;
    }
    out[0] = (float)psnr;
    out[1] = (float)ssim;
    out[2] = (float)NB;
  }
}

// host f32 -> f16 (round-to-nearest-even)
static unsigned short f2h(float f) {
  union { float f; unsigned u; } v; v.f = f;
  unsigned u = v.u;
  unsigned s = (u >> 16) & 0x8000u;
  int e = (int)((u >> 23) & 0xff) - 127 + 15;
  unsigned m = u & 0x7fffffu;
  if (e <= 0) return (unsigned short)s;
  if (e >= 31) return (unsigned short)(s | 0x7c00u);
  unsigned h = ((unsigned)e << 10) | (m >> 13);
  unsigned rem = m & 0x1fffu;
  if (rem > 0x1000u || (rem == 0x1000u && (h & 1u))) h++;
  return (unsigned short)(s | h);
}
// host f16 -> f32 (normals + zero)
static float h2f(unsigned short h) {
  unsigned se = (h >> 10) & 0x1f, m = h & 0x3ffu, s = ((unsigned)h & 0x8000u) << 16;
  union { unsigned u; float f; } v;
  if (se == 0) { v.u = s; return v.f; }
  v.u = s | ((se - 15 + 127) << 23) | (m << 13);
  return v.f;
}

extern "C" void kernel_launch(void* const* d_in, const int* in_sizes, int n_in,
                              void* d_out, int out_size, void* d_ws, size_t ws_size,
                              hipStream_t stream) {
  const float* pred = (const float*)d_in[0];
  const float* gt = (const float*)d_in[1];
  float* acc = (float*)d_ws;    // 8 floats

  double tt[11], s = 0.0;
  for (int i = 0; i < 11; ++i) {
    double x = i - 5;
    tt[i] = exp(-(x * x) / 4.5);
    s += tt[i];
  }
  float g[11];
  for (int i = 0; i < 11; ++i) g[i] = (float)(tt[i] / s);

  // f16 taps renormalized so the f16 values sum exactly to 1
  unsigned short hg[11];
  for (int i = 0; i < 11; ++i) hg[i] = f2h(g[i]);
  for (int pass = 0; pass < 3; ++pass) {
    double sum = 0.0;
    for (int i = 0; i < 11; ++i) sum += (double)h2f(hg[i]);
    hg[5] = f2h((float)((double)h2f(hg[5]) + (1.0 - sum)));
  }

  KArg ka;
  // even phase: (g0,g1)(g2,g3)(g4,g5)(g6,g7)(g8,g9)(g10,0)
  for (int j = 0; j < 5; ++j)
    ka.ge[j] = (unsigned)hg[2 * j] | ((unsigned)hg[2 * j + 1] << 16);
  ka.ge[5] = (unsigned)hg[10];
  // odd phase: (0,g0)(g1,g2)(g3,g4)(g5,g6)(g7,g8)(g9,g10)
  ka.go[0] = ((unsigned)hg[0]) << 16;
  for (int j = 1; j < 6; ++j)
    ka.go[j] = (unsigned)hg[2 * j - 1] | ((unsigned)hg[2 * j] << 16);

  // clamp-folded D-blur weights, f32, transposed: wlT[d][dout]
  for (int o = 0; o < DD; ++o)
    for (int d = 0; d < DD; ++d) {
      float w = 0.f;
      for (int k = 0; k < 11; ++k) {
        int j = o + k - 5;
        j = j < 0 ? 0 : (j > 15 ? 15 : j);
        if (j == d) w += g[k];
      }
      ka.wlT[d * DD + o] = w;
    }

  zero_acc_k<<<1, 64, 0, stream>>>(acc);
  fused_k<<<NB * 1024, NTHR, 0, stream>>>(pred, gt, acc, ka);
  final_k<<<1, 1, 0, stream>>>(acc, (float*)d_out);
}

// Round 12
// 251.310 us; speedup vs baseline: 1.0439x; 1.0086x over previous
//
#include <hip/hip_runtime.h>
#include <cmath>

// PSNR + 3D-SSIM, pred/gt (N=4, C=16->D, H=512, W=512) f32.
// R20 = R16 (best fused: 154.5us) + ONE change: stage only {S,D} (uint2,
// b64 ops) and derive the squared pairs IN the H phase via v_pk_mul_f16
// (blur is linear; S2/D2 staging was redundant data movement).
//   - sd: uint4 -> uint2 (9.7 -> 6.8 KB LDS); stage writes b128 -> b64;
//     H reads 12xb128 -> 12xb64 (+4 pk_mul per tap-pair, H threads only).
//   - LDS cycles/block-slice ~920 -> ~585 (LDS was the measured floor:
//     ~98us vs VALU 82us).
// R19's pk_fma D-accumulate is REVERTED (measured: identical VALU time,
// +18us dur -- register-pairing hurt scheduling). tmp/W/D-acc/SSIM and all
// metadata are R16 verbatim.

#define NB 4
#define DD 16
#define HH 512
#define WW 512
#define SLICE (HH * WW)
#define VOL (DD * SLICE)
#define C1F 0.0001f
#define C2F 0.0009f

#define TH 16
#define TW 16
#define SCOLS 26            // staged cols (TW+10)
#define NRP 13              // staged row-pairs ((TH+10)/2)
#define PW 14               // words per col-parity plane (13 + pad)
#define PLSTR 28            // row-pair stride (2 planes)
#define SDW (NRP * PLSTR)   // 364 uint2 = 2912 B
#define TMW (TH * PW)       // 224 uint4 = 3584 B
#define NTHR 256
#define SIT (NRP * SCOLS)   // 338 stage items per slice
#define XTRA (SIT - NTHR)   // 82
#define HITEMS 104          // 8 out-row-pairs x 13 col-pairs

typedef _Float16 h2v __attribute__((ext_vector_type(2)));

struct KArg {
  unsigned ge[6], go[6];   // f16x2 tap-pair coeffs, even/odd phase (renorm'd)
  float wlT[DD * DD];      // wlT[d*16+dout] = clamp-folded D weight (f32)
};

__device__ inline float dot2h(unsigned a, unsigned b, float c) {
#if __has_builtin(__builtin_amdgcn_fdot2)
  return __builtin_amdgcn_fdot2(__builtin_bit_cast(h2v, a),
                                __builtin_bit_cast(h2v, b), c, false);
#else
  h2v av = __builtin_bit_cast(h2v, a), bv = __builtin_bit_cast(h2v, b);
  return fmaf((float)av.y, (float)bv.y, fmaf((float)av.x, (float)bv.x, c));
#endif
}
__device__ inline unsigned pkh(float a, float b) {
  return __builtin_bit_cast(unsigned, __builtin_amdgcn_cvt_pkrtz(a, b));
}
__device__ inline unsigned pk2sq(unsigned a) {   // element-wise f16x2 square
  h2v v = __builtin_bit_cast(h2v, a);
  v = v * v;                                     // v_pk_mul_f16
  return __builtin_bit_cast(unsigned, v);
}
__device__ inline int iclamp(int v, int lo, int hi) {
  return v < lo ? lo : (v > hi ? hi : v);
}

__device__ inline float block_sum256(float v) {
#pragma unroll
  for (int o = 32; o > 0; o >>= 1) v += __shfl_down(v, o, 64);
  __shared__ float r[4];
  if ((threadIdx.x & 63) == 0) r[threadIdx.x >> 6] = v;
  __syncthreads();
  float out = 0.f;
  if (threadIdx.x == 0) {
#pragma unroll
    for (int i = 0; i < 4; ++i) out += r[i];
  }
  __syncthreads();
  return out;
}

__global__ void zero_acc_k(float* acc) {
  if (threadIdx.x < 8) acc[threadIdx.x] = 0.f;
}

__global__ __launch_bounds__(NTHR, 3) void fused_k(
    const float* __restrict__ pred, const float* __restrict__ gt,
    float* __restrict__ acc, KArg ka) {
  __shared__ uint2 sd[SDW];    // staged {S-pair, D-pair}  2.9 KB
  __shared__ uint4 tmp[TMW];   // H-blurred {hS,hD,hS2,hD2} 3.6 KB

  // XCD-aware bijective swizzle (kept from R16: FETCH 257->78 MB)
  int b0 = blockIdx.x;
  int b = (b0 & 7) * ((NB * 1024) >> 3) + (b0 >> 3);
  int tile = b & 1023;               // 32 h-tiles x 32 w-tiles
  int n = b >> 10;
  int th0 = (tile >> 5) * TH;
  int tw0 = (tile & 31) * TW;
  int t = threadIdx.x;

  // ---- stage metadata, slot 0 (item t, always < 338)
  int rp0 = t / SCOLS, x0 = t - rp0 * SCOLS;
  int gx0 = iclamp(tw0 + x0 - 5, 0, WW - 1);
  int go0a = iclamp(th0 + 2 * rp0 - 5, 0, HH - 1) * WW + gx0;
  int go0b = iclamp(th0 + 2 * rp0 - 4, 0, HH - 1) * WW + gx0;
  int w0i = (2 * rp0 + (x0 & 1)) * PW + (x0 >> 1);
  bool ox0 = (x0 >= 5) && (x0 < 5 + TW);
  float o0a = (ox0 && rp0 >= 3 && rp0 <= 10) ? 1.f : 0.f;  // row 2rp-5 owned
  float o0b = (ox0 && rp0 >= 2 && rp0 <= 9) ? 1.f : 0.f;   // row 2rp-4 owned
  // slot 1 (items 256..337 -> threads 174..255)
  int i1 = t + XTRA;
  bool has2 = (i1 >= NTHR);
  int rp1 = i1 / SCOLS, x1 = i1 - rp1 * SCOLS;
  int gx1 = iclamp(tw0 + x1 - 5, 0, WW - 1);
  int go1a = iclamp(th0 + 2 * rp1 - 5, 0, HH - 1) * WW + gx1;
  int go1b = iclamp(th0 + 2 * rp1 - 4, 0, HH - 1) * WW + gx1;
  int w1i = (2 * rp1 + (x1 & 1)) * PW + (x1 >> 1);
  bool ox1 = (x1 >= 5) && (x1 < 5 + TW);
  float o1a = (ox1 && rp1 >= 3 && rp1 <= 10) ? 1.f : 0.f;
  float o1b = (ox1 && rp1 >= 2 && rp1 <= 9) ? 1.f : 0.f;

  // ---- H metadata: item = (out-row-pair hm, col-pair hcp), m-minor
  bool hasH = (t < HITEMS);
  int hm = t & 7, hcp = t >> 3;
  int hrd = hm * PLSTR + hcp;        // plane0 read base (tap J adds J*PLSTR)
  int hwr = (2 * hm) * PW + hcp;     // row 2m write (+PW for row 2m+1)

  // ---- W metadata: thread owns px (t>>4, t&15) -- R16 mapping (broadcast
  // pairs on tmp reads)
  int wx = t & 15;
  int wrd = (t >> 4) * PW + (wx >> 1);
  unsigned cw[6];
#pragma unroll
  for (int J = 0; J < 6; ++J) cw[J] = (wx & 1) ? ka.go[J] : ka.ge[J];

  const float* pb = pred + (size_t)n * VOL;
  const float* qb = gt + (size_t)n * VOL;

  // prefetch slice 0
  float p0a = pb[go0a], p0b = pb[go0b], q0a = qb[go0a], q0b = qb[go0b];
  float p1a = 0.f, p1b = 0.f, q1a = 0.f, q1b = 0.f;
  if (has2) { p1a = pb[go1a]; p1b = pb[go1b]; q1a = qb[go1a]; q1b = qb[go1b]; }

  float psnr = 0.f;
  float a0[DD], a1[DD], a2[DD], a3[DD];
#pragma unroll
  for (int j = 0; j < DD; ++j) { a0[j] = a1[j] = a2[j] = a3[j] = 0.f; }

#pragma unroll 1
  for (int d = 0; d < DD; ++d) {
    // ---- stage slice d ({S,D} only; b64 writes)
    {
      float SA = p0a + q0a, DA = p0a - q0a;
      float SB = p0b + q0b, DB = p0b - q0b;
      psnr = fmaf(o0a, DA * DA, psnr);
      psnr = fmaf(o0b, DB * DB, psnr);
      sd[w0i] = make_uint2(pkh(SA, SB), pkh(DA, DB));
    }
    if (has2) {
      float SA = p1a + q1a, DA = p1a - q1a;
      float SB = p1b + q1b, DB = p1b - q1b;
      psnr = fmaf(o1a, DA * DA, psnr);
      psnr = fmaf(o1b, DB * DB, psnr);
      sd[w1i] = make_uint2(pkh(SA, SB), pkh(DA, DB));
    }
    __syncthreads();   // B1: sd ready; also fences tmp vs prev iter's W reads

    // prefetch slice d+1 (hides under H+W; consumed next iter after B2+W)
    if (d < DD - 1) {
      const float* P = pb + (size_t)(d + 1) * SLICE;
      const float* Q = qb + (size_t)(d + 1) * SLICE;
      p0a = P[go0a]; p0b = P[go0b]; q0a = Q[go0a]; q0b = Q[go0b];
      if (has2) { p1a = P[go1a]; p1b = P[go1b]; q1a = Q[go1a]; q1b = Q[go1b]; }
    }

    // ---- H-blur (vertical), fused row parities: 12 b64 reads -> 2 b128
    // writes; squared pairs formed in-register (v_pk_mul_f16)
    if (hasH) {
      float e0[4] = {0, 0, 0, 0}, e1[4] = {0, 0, 0, 0};   // row 2m, col 2cp / 2cp+1
      float r0[4] = {0, 0, 0, 0}, r1[4] = {0, 0, 0, 0};   // row 2m+1
#pragma unroll
      for (int J = 0; J < 6; ++J) {
        uint2 ve = sd[hrd + J * PLSTR];        // col 2cp,  row-pair m+J
        uint2 vo = sd[hrd + J * PLSTR + PW];   // col 2cp+1
        unsigned ves = pk2sq(ve.x), ved = pk2sq(ve.y);
        unsigned vos = pk2sq(vo.x), vod = pk2sq(vo.y);
        unsigned cge = ka.ge[J], cgo = ka.go[J];
        e0[0] = dot2h(cge, ve.x, e0[0]); e0[1] = dot2h(cge, ve.y, e0[1]);
        e0[2] = dot2h(cge, ves, e0[2]);  e0[3] = dot2h(cge, ved, e0[3]);
        r0[0] = dot2h(cgo, ve.x, r0[0]); r0[1] = dot2h(cgo, ve.y, r0[1]);
        r0[2] = dot2h(cgo, ves, r0[2]);  r0[3] = dot2h(cgo, ved, r0[3]);
        e1[0] = dot2h(cge, vo.x, e1[0]); e1[1] = dot2h(cge, vo.y, e1[1]);
        e1[2] = dot2h(cge, vos, e1[2]);  e1[3] = dot2h(cge, vod, e1[3]);
        r1[0] = dot2h(cgo, vo.x, r1[0]); r1[1] = dot2h(cgo, vo.y, r1[1]);
        r1[2] = dot2h(cgo, vos, r1[2]);  r1[3] = dot2h(cgo, vod, r1[3]);
      }
      tmp[hwr] = make_uint4(pkh(e0[0], e1[0]), pkh(e0[1], e1[1]),
                            pkh(e0[2], e1[2]), pkh(e0[3], e1[3]));
      tmp[hwr + PW] = make_uint4(pkh(r0[0], r1[0]), pkh(r0[1], r1[1]),
                                 pkh(r0[2], r1[2]), pkh(r0[3], r1[3]));
    }
    __syncthreads();   // B2: tmp ready; also separates H's sd reads from the
                       // NEXT iteration's stage writes (single buffer safe)

    // ---- W-blur at owned px: 6 b128 reads (2-way broadcast), 24 dot2
    float w0 = 0.f, w1 = 0.f, w2 = 0.f, w3 = 0.f;
#pragma unroll
    for (int J = 0; J < 6; ++J) {
      uint4 v = tmp[wrd + J];
      w0 = dot2h(cw[J], v.x, w0); w1 = dot2h(cw[J], v.y, w1);
      w2 = dot2h(cw[J], v.z, w2); w3 = dot2h(cw[J], v.w, w3);
    }
    // ---- D-accumulate (f32 scalar fma, weights uniform -> s_load + v_fma)
    const float* wl = ka.wlT + d * DD;
#pragma unroll
    for (int o = 0; o < DD; ++o) {
      float w = wl[o];
      a0[o] = fmaf(w, w0, a0[o]);
      a1[o] = fmaf(w, w1, a1[o]);
      a2[o] = fmaf(w, w2, a2[o]);
      a3[o] = fmaf(w, w3, a3[o]);
    }
  }

  // ---- SSIM over the 16 douts of this px
  float ssum = 0.f;
#pragma unroll
  for (int j = 0; j < DD; ++j) {
    float Sb = a0[j], Db = a1[j], B1 = a2[j], B2 = a3[j];
    float SS = Sb * Sb, DDm = Db * Db;
    float m12_2 = (SS - DDm) * 0.5f;     // 2*mu1*mu2
    float msq   = (SS + DDm) * 0.5f;     // mu1^2 + mu2^2
    float Epq   = (B1 - B2) * 0.25f;     // E[pq]
    float Esum  = (B1 + B2) * 0.5f;      // E[p^2+q^2]
    float sig12_2 = 2.f * Epq - m12_2;   // 2*sigma12
    float svar    = Esum - msq;          // sigma1^2 + sigma2^2
    float num = (m12_2 + C1F) * (sig12_2 + C2F);
    float den = (msq + C1F) * (svar + C2F);
    ssum += num / den;
  }
  float bs = block_sum256(ssum);
  if (t == 0) atomicAdd(&acc[4 + n], bs);
  float bp = block_sum256(psnr);
  if (t == 0) atomicAdd(&acc[n], bp);
}

__global__ void final_k(const float* __restrict__ acc, float* __restrict__ out) {
  if (threadIdx.x == 0 && blockIdx.x == 0) {
    double psnr = 0.0, ssim = 0.0;
    for (int n = 0; n < NB; ++n) {
      double mse = (double)acc[n] / (double)VOL;
      psnr += 10.0 * log10(1.0 / mse);
      ssim += (double)acc[4 + n] / (double)VOL;
    }
    out[0] = (float)psnr;
    out[1] = (float)ssim;
    out[2] = (float)NB;
  }
}

// host f32 -> f16 (round-to-nearest-even)
static unsigned short f2h(float f) {
  union { float f; unsigned u; } v; v.f = f;
  unsigned u = v.u;
  unsigned s = (u >> 16) & 0x8000u;
  int e = (int)((u >> 23) & 0xff) - 127 + 15;
  unsigned m = u & 0x7fffffu;
  if (e <= 0) return (unsigned short)s;
  if (e >= 31) return (unsigned short)(s | 0x7c00u);
  unsigned h = ((unsigned)e << 10) | (m >> 13);
  unsigned rem = m & 0x1fffu;
  if (rem > 0x1000u || (rem == 0x1000u && (h & 1u))) h++;
  return (unsigned short)(s | h);
}
// host f16 -> f32 (normals + zero)
static float h2f(unsigned short h) {
  unsigned se = (h >> 10) & 0x1f, m = h & 0x3ffu, s = ((unsigned)h & 0x8000u) << 16;
  union { unsigned u; float f; } v;
  if (se == 0) { v.u = s; return v.f; }
  v.u = s | ((se - 15 + 127) << 23) | (m << 13);
  return v.f;
}

extern "C" void kernel_launch(void* const* d_in, const int* in_sizes, int n_in,
                              void* d_out, int out_size, void* d_ws, size_t ws_size,
                              hipStream_t stream) {
  const float* pred = (const float*)d_in[0];
  const float* gt = (const float*)d_in[1];
  float* acc = (float*)d_ws;    // 8 floats

  double tt[11], s = 0.0;
  for (int i = 0; i < 11; ++i) {
    double x = i - 5;
    tt[i] = exp(-(x * x) / 4.5);
    s += tt[i];
  }
  float g[11];
  for (int i = 0; i < 11; ++i) g[i] = (float)(tt[i] / s);

  // f16 taps renormalized so the f16 values sum exactly to 1
  unsigned short hg[11];
  for (int i = 0; i < 11; ++i) hg[i] = f2h(g[i]);
  for (int pass = 0; pass < 3; ++pass) {
    double sum = 0.0;
    for (int i = 0; i < 11; ++i) sum += (double)h2f(hg[i]);
    hg[5] = f2h((float)((double)h2f(hg[5]) + (1.0 - sum)));
  }

  KArg ka;
  // even phase: (g0,g1)(g2,g3)(g4,g5)(g6,g7)(g8,g9)(g10,0)
  for (int j = 0; j < 5; ++j)
    ka.ge[j] = (unsigned)hg[2 * j] | ((unsigned)hg[2 * j + 1] << 16);
  ka.ge[5] = (unsigned)hg[10];
  // odd phase: (0,g0)(g1,g2)(g3,g4)(g5,g6)(g7,g8)(g9,g10)
  ka.go[0] = ((unsigned)hg[0]) << 16;
  for (int j = 1; j < 6; ++j)
    ka.go[j] = (unsigned)hg[2 * j - 1] | ((unsigned)hg[2 * j] << 16);

  // clamp-folded D-blur weights, f32, transposed: wlT[d][dout]
  for (int o = 0; o < DD; ++o)
    for (int d = 0; d < DD; ++d) {
      float w = 0.f;
      for (int k = 0; k < 11; ++k) {
        int j = o + k - 5;
        j = j < 0 ? 0 : (j > 15 ? 15 : j);
        if (j == d) w += g[k];
      }
      ka.wlT[d * DD + o] = w;
    }

  zero_acc_k<<<1, 64, 0, stream>>>(acc);
  fused_k<<<NB * 1024, NTHR, 0, stream>>>(pred, gt, acc, ka);
  final_k<<<1, 1, 0, stream>>>(acc, (float*)d_out);
}

// Round 13
// 250.656 us; speedup vs baseline: 1.0466x; 1.0026x over previous
//
#include <hip/hip_runtime.h>
#include <cmath>

// PSNR + 3D-SSIM, pred/gt (N=4, C=16->D, H=512, W=512) f32.
// R21 = R20 (155us; {S,D}-only staging + in-register squares, XCD swizzle,
// absmax 0.0067) + slice-paired dot2 D-accumulate:
//   Process 2 slices per outer iteration (8 iters, body x2 -- a 2x unroll
//   only, NOT R15's fatal 16x+cap combo). Save slice-A's W outputs (4
//   regs), pack A/B pairs (4 pkh), accumulate with 64 dot2 per pair
//   instead of 128 fma. f16 d-pair weights w2[m][o] (per-dout renorm'd,
//   validated at absmax 0.0153 in R10/12/13). Accumulators stay f32x64;
//   launch_bounds (256,3) (reg ceiling 160, est ~140 -> no spill).
// D-accumulate was the largest VALU term (64/136 per thread-slice); VALU
// (82us @ 53%) is the measured dominant pipe.

#define NB 4
#define DD 16
#define HH 512
#define WW 512
#define SLICE (HH * WW)
#define VOL (DD * SLICE)
#define C1F 0.0001f
#define C2F 0.0009f

#define TH 16
#define TW 16
#define SCOLS 26            // staged cols (TW+10)
#define NRP 13              // staged row-pairs ((TH+10)/2)
#define PW 14               // words per col-parity plane (13 + pad)
#define PLSTR 28            // row-pair stride (2 planes)
#define SDW (NRP * PLSTR)   // 364 uint2 = 2912 B
#define TMW (TH * PW)       // 224 uint4 = 3584 B
#define NTHR 256
#define SIT (NRP * SCOLS)   // 338 stage items per slice
#define XTRA (SIT - NTHR)   // 82
#define HITEMS 104          // 8 out-row-pairs x 13 col-pairs

typedef _Float16 h2v __attribute__((ext_vector_type(2)));

struct KArg {
  unsigned ge[6], go[6];   // f16x2 tap-pair coeffs, even/odd phase (renorm'd)
  unsigned w2[128];        // [m][o] = f16x2 (wl[2m][o], wl[2m+1][o])
};

__device__ inline float dot2h(unsigned a, unsigned b, float c) {
#if __has_builtin(__builtin_amdgcn_fdot2)
  return __builtin_amdgcn_fdot2(__builtin_bit_cast(h2v, a),
                                __builtin_bit_cast(h2v, b), c, false);
#else
  h2v av = __builtin_bit_cast(h2v, a), bv = __builtin_bit_cast(h2v, b);
  return fmaf((float)av.y, (float)bv.y, fmaf((float)av.x, (float)bv.x, c));
#endif
}
__device__ inline unsigned pkh(float a, float b) {
  return __builtin_bit_cast(unsigned, __builtin_amdgcn_cvt_pkrtz(a, b));
}
__device__ inline unsigned pk2sq(unsigned a) {   // element-wise f16x2 square
  h2v v = __builtin_bit_cast(h2v, a);
  v = v * v;                                     // v_pk_mul_f16
  return __builtin_bit_cast(unsigned, v);
}
__device__ inline int iclamp(int v, int lo, int hi) {
  return v < lo ? lo : (v > hi ? hi : v);
}

__device__ inline float block_sum256(float v) {
#pragma unroll
  for (int o = 32; o > 0; o >>= 1) v += __shfl_down(v, o, 64);
  __shared__ float r[4];
  if ((threadIdx.x & 63) == 0) r[threadIdx.x >> 6] = v;
  __syncthreads();
  float out = 0.f;
  if (threadIdx.x == 0) {
#pragma unroll
    for (int i = 0; i < 4; ++i) out += r[i];
  }
  __syncthreads();
  return out;
}

__global__ void zero_acc_k(float* acc) {
  if (threadIdx.x < 8) acc[threadIdx.x] = 0.f;
}

__global__ __launch_bounds__(NTHR, 3) void fused_k(
    const float* __restrict__ pred, const float* __restrict__ gt,
    float* __restrict__ acc, KArg ka) {
  __shared__ uint2 sd[SDW];    // staged {S-pair, D-pair}  2.9 KB
  __shared__ uint4 tmp[TMW];   // H-blurred {hS,hD,hS2,hD2} 3.6 KB

  // XCD-aware bijective swizzle (kept from R16: FETCH 257->78 MB)
  int b0 = blockIdx.x;
  int b = (b0 & 7) * ((NB * 1024) >> 3) + (b0 >> 3);
  int tile = b & 1023;               // 32 h-tiles x 32 w-tiles
  int n = b >> 10;
  int th0 = (tile >> 5) * TH;
  int tw0 = (tile & 31) * TW;
  int t = threadIdx.x;

  // ---- stage metadata, slot 0 (item t, always < 338)
  int rp0 = t / SCOLS, x0 = t - rp0 * SCOLS;
  int gx0 = iclamp(tw0 + x0 - 5, 0, WW - 1);
  int go0a = iclamp(th0 + 2 * rp0 - 5, 0, HH - 1) * WW + gx0;
  int go0b = iclamp(th0 + 2 * rp0 - 4, 0, HH - 1) * WW + gx0;
  int w0i = (2 * rp0 + (x0 & 1)) * PW + (x0 >> 1);
  bool ox0 = (x0 >= 5) && (x0 < 5 + TW);
  float o0a = (ox0 && rp0 >= 3 && rp0 <= 10) ? 1.f : 0.f;  // row 2rp-5 owned
  float o0b = (ox0 && rp0 >= 2 && rp0 <= 9) ? 1.f : 0.f;   // row 2rp-4 owned
  // slot 1 (items 256..337 -> threads 174..255)
  int i1 = t + XTRA;
  bool has2 = (i1 >= NTHR);
  int rp1 = i1 / SCOLS, x1 = i1 - rp1 * SCOLS;
  int gx1 = iclamp(tw0 + x1 - 5, 0, WW - 1);
  int go1a = iclamp(th0 + 2 * rp1 - 5, 0, HH - 1) * WW + gx1;
  int go1b = iclamp(th0 + 2 * rp1 - 4, 0, HH - 1) * WW + gx1;
  int w1i = (2 * rp1 + (x1 & 1)) * PW + (x1 >> 1);
  bool ox1 = (x1 >= 5) && (x1 < 5 + TW);
  float o1a = (ox1 && rp1 >= 3 && rp1 <= 10) ? 1.f : 0.f;
  float o1b = (ox1 && rp1 >= 2 && rp1 <= 9) ? 1.f : 0.f;

  // ---- H metadata: item = (out-row-pair hm, col-pair hcp), m-minor
  bool hasH = (t < HITEMS);
  int hm = t & 7, hcp = t >> 3;
  int hrd = hm * PLSTR + hcp;        // plane0 read base (tap J adds J*PLSTR)
  int hwr = (2 * hm) * PW + hcp;     // row 2m write (+PW for row 2m+1)

  // ---- W metadata: thread owns px (t>>4, t&15) -- R16 mapping (broadcast
  // pairs on tmp reads)
  int wx = t & 15;
  int wrd = (t >> 4) * PW + (wx >> 1);
  unsigned cw[6];
#pragma unroll
  for (int J = 0; J < 6; ++J) cw[J] = (wx & 1) ? ka.go[J] : ka.ge[J];

  const float* pb = pred + (size_t)n * VOL;
  const float* qb = gt + (size_t)n * VOL;

  // prefetch slice 0
  float p0a = pb[go0a], p0b = pb[go0b], q0a = qb[go0a], q0b = qb[go0b];
  float p1a = 0.f, p1b = 0.f, q1a = 0.f, q1b = 0.f;
  if (has2) { p1a = pb[go1a]; p1b = pb[go1b]; q1a = qb[go1a]; q1b = qb[go1b]; }

  float psnr = 0.f;
  float a0[DD], a1[DD], a2[DD], a3[DD];
#pragma unroll
  for (int j = 0; j < DD; ++j) { a0[j] = a1[j] = a2[j] = a3[j] = 0.f; }

// One slice: stage -> B1 -> prefetch -> H -> B2 -> W (leaves ww0..ww3).
// Verbatim R20 body.
#define DO_SLICE(D)                                                         \
  {                                                                         \
    float SA = p0a + q0a, DA = p0a - q0a;                                   \
    float SB = p0b + q0b, DB = p0b - q0b;                                   \
    psnr = fmaf(o0a, DA * DA, psnr);                                        \
    psnr = fmaf(o0b, DB * DB, psnr);                                        \
    sd[w0i] = make_uint2(pkh(SA, SB), pkh(DA, DB));                         \
  }                                                                         \
  if (has2) {                                                               \
    float SA = p1a + q1a, DA = p1a - q1a;                                   \
    float SB = p1b + q1b, DB = p1b - q1b;                                   \
    psnr = fmaf(o1a, DA * DA, psnr);                                        \
    psnr = fmaf(o1b, DB * DB, psnr);                                        \
    sd[w1i] = make_uint2(pkh(SA, SB), pkh(DA, DB));                         \
  }                                                                         \
  __syncthreads(); /* B1: sd ready; fences tmp vs prev W reads */           \
  if ((D) < DD - 1) {                                                       \
    const float* P = pb + (size_t)((D) + 1) * SLICE;                        \
    const float* Q = qb + (size_t)((D) + 1) * SLICE;                        \
    p0a = P[go0a]; p0b = P[go0b]; q0a = Q[go0a]; q0b = Q[go0b];             \
    if (has2) { p1a = P[go1a]; p1b = P[go1b]; q1a = Q[go1a]; q1b = Q[go1b]; } \
  }                                                                         \
  if (hasH) {                                                               \
    float e0[4] = {0, 0, 0, 0}, e1[4] = {0, 0, 0, 0};                       \
    float r0[4] = {0, 0, 0, 0}, r1[4] = {0, 0, 0, 0};                       \
    _Pragma("unroll")                                                       \
    for (int J = 0; J < 6; ++J) {                                           \
      uint2 ve = sd[hrd + J * PLSTR];                                       \
      uint2 vo = sd[hrd + J * PLSTR + PW];                                  \
      unsigned ves = pk2sq(ve.x), ved = pk2sq(ve.y);                        \
      unsigned vos = pk2sq(vo.x), vod = pk2sq(vo.y);                        \
      unsigned cge = ka.ge[J], cgo = ka.go[J];                              \
      e0[0] = dot2h(cge, ve.x, e0[0]); e0[1] = dot2h(cge, ve.y, e0[1]);     \
      e0[2] = dot2h(cge, ves, e0[2]);  e0[3] = dot2h(cge, ved, e0[3]);      \
      r0[0] = dot2h(cgo, ve.x, r0[0]); r0[1] = dot2h(cgo, ve.y, r0[1]);     \
      r0[2] = dot2h(cgo, ves, r0[2]);  r0[3] = dot2h(cgo, ved, r0[3]);      \
      e1[0] = dot2h(cge, vo.x, e1[0]); e1[1] = dot2h(cge, vo.y, e1[1]);     \
      e1[2] = dot2h(cge, vos, e1[2]);  e1[3] = dot2h(cge, vod, e1[3]);      \
      r1[0] = dot2h(cgo, vo.x, r1[0]); r1[1] = dot2h(cgo, vo.y, r1[1]);     \
      r1[2] = dot2h(cgo, vos, r1[2]);  r1[3] = dot2h(cgo, vod, r1[3]);      \
    }                                                                       \
    tmp[hwr] = make_uint4(pkh(e0[0], e1[0]), pkh(e0[1], e1[1]),             \
                          pkh(e0[2], e1[2]), pkh(e0[3], e1[3]));            \
    tmp[hwr + PW] = make_uint4(pkh(r0[0], r1[0]), pkh(r0[1], r1[1]),        \
                               pkh(r0[2], r1[2]), pkh(r0[3], r1[3]));       \
  }                                                                         \
  __syncthreads(); /* B2: tmp ready; separates sd reads from next stage */  \
  ww0 = 0.f; ww1 = 0.f; ww2 = 0.f; ww3 = 0.f;                               \
  _Pragma("unroll")                                                         \
  for (int J = 0; J < 6; ++J) {                                             \
    uint4 v = tmp[wrd + J];                                                 \
    ww0 = dot2h(cw[J], v.x, ww0); ww1 = dot2h(cw[J], v.y, ww1);             \
    ww2 = dot2h(cw[J], v.z, ww2); ww3 = dot2h(cw[J], v.w, ww3);             \
  }

  float ww0, ww1, ww2, ww3;
#pragma unroll 1
  for (int dd = 0; dd < DD; dd += 2) {
    // slice A (even)
    DO_SLICE(dd)
    float wa0 = ww0, wa1 = ww1, wa2 = ww2, wa3 = ww3;
    // slice B (odd)
    DO_SLICE(dd + 1)
    // pack A/B pairs, accumulate both slices with dot2 (f16 pair weights)
    unsigned pw0 = pkh(wa0, ww0), pw1 = pkh(wa1, ww1);
    unsigned pw2 = pkh(wa2, ww2), pw3 = pkh(wa3, ww3);
    const unsigned* w2p = ka.w2 + (dd >> 1) * DD;   // uniform -> s_load
#pragma unroll
    for (int o = 0; o < DD; ++o) {
      unsigned c = w2p[o];
      a0[o] = dot2h(c, pw0, a0[o]);
      a1[o] = dot2h(c, pw1, a1[o]);
      a2[o] = dot2h(c, pw2, a2[o]);
      a3[o] = dot2h(c, pw3, a3[o]);
    }
  }
#undef DO_SLICE

  // ---- SSIM over the 16 douts of this px
  float ssum = 0.f;
#pragma unroll
  for (int j = 0; j < DD; ++j) {
    float Sb = a0[j], Db = a1[j], B1 = a2[j], B2 = a3[j];
    float SS = Sb * Sb, DDm = Db * Db;
    float m12_2 = (SS - DDm) * 0.5f;     // 2*mu1*mu2
    float msq   = (SS + DDm) * 0.5f;     // mu1^2 + mu2^2
    float Epq   = (B1 - B2) * 0.25f;     // E[pq]
    float Esum  = (B1 + B2) * 0.5f;      // E[p^2+q^2]
    float sig12_2 = 2.f * Epq - m12_2;   // 2*sigma12
    float svar    = Esum - msq;          // sigma1^2 + sigma2^2
    float num = (m12_2 + C1F) * (sig12_2 + C2F);
    float den = (msq + C1F) * (svar + C2F);
    ssum += num / den;
  }
  float bs = block_sum256(ssum);
  if (t == 0) atomicAdd(&acc[4 + n], bs);
  float bp = block_sum256(psnr);
  if (t == 0) atomicAdd(&acc[n], bp);
}

__global__ void final_k(const float* __restrict__ acc, float* __restrict__ out) {
  if (threadIdx.x == 0 && blockIdx.x == 0) {
    double psnr = 0.0, ssim = 0.0;
    for (int n = 0; n < NB; ++n) {
      double mse = (double)acc[n] / (double)VOL;
      psnr += 10.0 * log10(1.0 / mse);
      ssim += (double)acc[4 + n] / (double)VOL;
    }
    out[0] = (float)psnr;
    out[1] = (float)ssim;
    out[2] = (float)NB;
  }
}

// host f32 -> f16 (round-to-nearest-even)
static unsigned short f2h(float f) {
  union { float f; unsigned u; } v; v.f = f;
  unsigned u = v.u;
  unsigned s = (u >> 16) & 0x8000u;
  int e = (int)((u >> 23) & 0xff) - 127 + 15;
  unsigned m = u & 0x7fffffu;
  if (e <= 0) return (unsigned short)s;
  if (e >= 31) return (unsigned short)(s | 0x7c00u);
  unsigned h = ((unsigned)e << 10) | (m >> 13);
  unsigned rem = m & 0x1fffu;
  if (rem > 0x1000u || (rem == 0x1000u && (h & 1u))) h++;
  return (unsigned short)(s | h);
}
// host f16 -> f32 (normals + zero)
static float h2f(unsigned short h) {
  unsigned se = (h >> 10) & 0x1f, m = h & 0x3ffu, s = ((unsigned)h & 0x8000u) << 16;
  union { unsigned u; float f; } v;
  if (se == 0) { v.u = s; return v.f; }
  v.u = s | ((se - 15 + 127) << 23) | (m << 13);
  return v.f;
}

extern "C" void kernel_launch(void* const* d_in, const int* in_sizes, int n_in,
                              void* d_out, int out_size, void* d_ws, size_t ws_size,
                              hipStream_t stream) {
  const float* pred = (const float*)d_in[0];
  const float* gt = (const float*)d_in[1];
  float* acc = (float*)d_ws;    // 8 floats

  double tt[11], s = 0.0;
  for (int i = 0; i < 11; ++i) {
    double x = i - 5;
    tt[i] = exp(-(x * x) / 4.5);
    s += tt[i];
  }
  float g[11];
  for (int i = 0; i < 11; ++i) g[i] = (float)(tt[i] / s);

  // f16 taps renormalized so the f16 values sum exactly to 1
  unsigned short hg[11];
  for (int i = 0; i < 11; ++i) hg[i] = f2h(g[i]);
  for (int pass = 0; pass < 3; ++pass) {
    double sum = 0.0;
    for (int i = 0; i < 11; ++i) sum += (double)h2f(hg[i]);
    hg[5] = f2h((float)((double)h2f(hg[5]) + (1.0 - sum)));
  }

  KArg ka;
  // even phase: (g0,g1)(g2,g3)(g4,g5)(g6,g7)(g8,g9)(g10,0)
  for (int j = 0; j < 5; ++j)
    ka.ge[j] = (unsigned)hg[2 * j] | ((unsigned)hg[2 * j + 1] << 16);
  ka.ge[5] = (unsigned)hg[10];
  // odd phase: (0,g0)(g1,g2)(g3,g4)(g5,g6)(g7,g8)(g9,g10)
  ka.go[0] = ((unsigned)hg[0]) << 16;
  for (int j = 1; j < 6; ++j)
    ka.go[j] = (unsigned)hg[2 * j - 1] | ((unsigned)hg[2 * j] << 16);

  // clamp-folded D-blur weights wl[d][o]; f16 per-dout renorm; pair-packed
  // as w2[m][o] = (wl[2m][o], wl[2m+1][o])
  float wl[DD][DD];
  for (int o = 0; o < DD; ++o)
    for (int d = 0; d < DD; ++d) {
      float w = 0.f;
      for (int k = 0; k < 11; ++k) {
        int j = o + k - 5;
        j = j < 0 ? 0 : (j > 15 ? 15 : j);
        if (j == d) w += g[k];
      }
      wl[d][o] = w;
    }
  for (int o = 0; o < DD; ++o) {
    unsigned short wv[DD];
    int dmx = 0;
    for (int d = 0; d < DD; ++d) {
      wv[d] = f2h(wl[d][o]);
      if (wl[d][o] > wl[dmx][o]) dmx = d;
    }
    for (int pass = 0; pass < 3; ++pass) {
      double sum = 0.0;
      for (int d = 0; d < DD; ++d) sum += (double)h2f(wv[d]);
      wv[dmx] = f2h((float)((double)h2f(wv[dmx]) + (1.0 - sum)));
    }
    for (int m = 0; m < 8; ++m)
      ka.w2[m * DD + o] = (unsigned)wv[2 * m] | ((unsigned)wv[2 * m + 1] << 16);
  }

  zero_acc_k<<<1, 64, 0, stream>>>(acc);
  fused_k<<<NB * 1024, NTHR, 0, stream>>>(pred, gt, acc, ka);
  final_k<<<1, 1, 0, stream>>>(acc, (float*)d_out);
}